// Round 3
// baseline (1836.082 us; speedup 1.0000x reference)
//
#include <hip/hip_runtime.h>
#include <hip/hip_bf16.h>

// Expert-choice MoE, MI355X. B=4,S=4096,D=1024,E=8,I=4096, k=1024 per (b,e).
// R3: dtype-self-detecting build. Device probe decides fp32-vs-bf16 input
// encoding; inputs converted to canonical bf16 ws buffers for the MFMA GEMMs;
// gate/softmax reads original data at native precision (fp64 accumulate) so
// top-k selection matches the numpy reference exactly.

#define B_ 4
#define S_ 4096
#define D_ 1024
#define E_ 8
#define I_ 4096
#define KCAP 1024
#define NGROUPS 32

typedef __bf16 bf16x8 __attribute__((ext_vector_type(8)));
typedef float floatx4 __attribute__((ext_vector_type(4)));

__device__ __forceinline__ float bf2f(unsigned short h) {
  union { unsigned int u; float f; } v; v.u = ((unsigned int)h) << 16; return v.f;
}
__device__ __forceinline__ unsigned short f2bf(float f) {
  union { float f; unsigned int u; } v; v.f = f;
  unsigned int r = (v.u + 0x7fffu + ((v.u >> 16) & 1u)) >> 16;
  return (unsigned short)r;
}

// ---------------- 0. dtype probe: is d_in[0] fp32 (1) or bf16 (0)? ----------------
// Even bf16-indices of an fp32 buffer are low mantissa halves -> random exponents.
__global__ __launch_bounds__(256) void probe_dtype_k(const unsigned short* __restrict__ xr,
                                                     int* __restrict__ flag) {
  __shared__ unsigned int cnt;
  if (threadIdx.x == 0) cnt = 0;
  __syncthreads();
  unsigned int local = 0;
  for (int j = 0; j < 16; ++j) {
    int k = threadIdx.x * 16 + j;          // sample index
    unsigned short u = xr[2 * k];          // even bf16 position
    unsigned int expf = (u >> 7) & 0xFF;
    if (expf >= 0x90 && expf != 0xFF) local++;  // |v| >= 2^17 (wild for N(0,1))
    if (expf == 0xFF) local++;                   // inf/nan pattern
  }
  atomicAdd(&cnt, local);
  __syncthreads();
  if (threadIdx.x == 0) *flag = (cnt > 256u) ? 1 : 0;
}

// ---------------- 0b. convert input tensor -> canonical bf16 ----------------
__global__ __launch_bounds__(256) void conv_in_k(const void* __restrict__ src,
                                                 unsigned short* __restrict__ dst,
                                                 const int* __restrict__ flag) {
  const int isf32 = *flag;
  size_t i = ((size_t)blockIdx.x * 256 + threadIdx.x) * 8;
  if (isf32) {
    const float* s = (const float*)src;
    float4 a = *(const float4*)(s + i);
    float4 b = *(const float4*)(s + i + 4);
    ushort4 o0, o1;
    o0.x = f2bf(a.x); o0.y = f2bf(a.y); o0.z = f2bf(a.z); o0.w = f2bf(a.w);
    o1.x = f2bf(b.x); o1.y = f2bf(b.y); o1.z = f2bf(b.z); o1.w = f2bf(b.w);
    *(ushort4*)(dst + i) = o0;
    *(ushort4*)(dst + i + 4) = o1;
  } else {
    const uint4* s = (const uint4*)src;
    *(uint4*)(dst + i) = s[i / 8];
  }
}

// ---------------- 1. gate logits + softmax (fp64, native-precision reads) ----------------
__global__ __launch_bounds__(256) void gate_softmax_k(
    const void* __restrict__ xr, const void* __restrict__ gwr,
    const int* __restrict__ flag, double* __restrict__ aff) {
  const int isf32 = *flag;
  const int wave = threadIdx.x >> 6, lane = threadIdx.x & 63;
  const int token = blockIdx.x * 4 + wave;
  double acc[E_];
#pragma unroll
  for (int e2 = 0; e2 < E_; ++e2) acc[e2] = 0.0;
  for (int j = 0; j < 16; ++j) {
    int k = lane + 64 * j;
    double xv, wv[E_];
    if (isf32) {
      xv = (double)((const float*)xr)[(size_t)token * D_ + k];
#pragma unroll
      for (int e2 = 0; e2 < E_; ++e2) wv[e2] = (double)((const float*)gwr)[e2 * D_ + k];
    } else {
      xv = (double)bf2f(((const unsigned short*)xr)[(size_t)token * D_ + k]);
#pragma unroll
      for (int e2 = 0; e2 < E_; ++e2) wv[e2] = (double)bf2f(((const unsigned short*)gwr)[e2 * D_ + k]);
    }
#pragma unroll
    for (int e2 = 0; e2 < E_; ++e2) acc[e2] += xv * wv[e2];
  }
#pragma unroll
  for (int e2 = 0; e2 < E_; ++e2) {
#pragma unroll
    for (int off = 1; off < 64; off <<= 1) acc[e2] += __shfl_xor(acc[e2], off);
  }
  if (lane < E_) {
    double mx = acc[0];
#pragma unroll
    for (int e2 = 1; e2 < E_; ++e2) mx = acc[e2] > mx ? acc[e2] : mx;
    double ssum = 0.0;
#pragma unroll
    for (int e2 = 0; e2 < E_; ++e2) ssum += exp(acc[e2] - mx);
    double p = exp(acc[lane] - mx) / ssum;
    int b = token >> 12, s = token & (S_ - 1);
    aff[((size_t)b * E_ + lane) * S_ + s] = p;
  }
}

// ---------------- 2. top-1024-of-4096 radix select per (b,e) ----------------
__global__ __launch_bounds__(256) void topk_sel_k(
    const double* __restrict__ aff, int* __restrict__ sel_idx, float* __restrict__ sel_gate) {
  __shared__ unsigned long long keys[4096];
  __shared__ unsigned int hist[256];
  __shared__ unsigned int bcast[3];
  const int g = blockIdx.x, t = threadIdx.x;
  const int e = g >> 2, b = g & 3;  // expert-major group order
  const double* ap = aff + ((size_t)b * E_ + e) * S_;
  for (int j = 0; j < 16; ++j) {
    int i = t + 256 * j;
    keys[i] = __double_as_longlong(ap[i]);  // positive doubles: uint64 order == value order
  }
  __syncthreads();
  unsigned long long prefix = 0ull;
  int remaining = KCAP;
  for (int p = 7; p >= 0; --p) {
    hist[t] = 0;
    __syncthreads();
    unsigned long long mask_hi = (p == 7) ? 0ull : (~0ull << ((p + 1) * 8));
    for (int j = 0; j < 16; ++j) {
      unsigned long long key = keys[t + 256 * j];
      if ((key & mask_hi) == prefix)
        atomicAdd(&hist[(unsigned)(key >> (p * 8)) & 255u], 1u);
    }
    __syncthreads();
    if (t == 0) {
      unsigned cum = 0; int bsel = 0;
      for (int v = 255; v >= 0; --v) {
        unsigned cc = hist[v];
        if (cum + cc >= (unsigned)remaining) { bsel = v; break; }
        cum += cc;
      }
      bcast[0] = (unsigned)bsel; bcast[1] = cum;
    }
    __syncthreads();
    prefix |= ((unsigned long long)bcast[0]) << (p * 8);
    remaining -= (int)bcast[1];
    __syncthreads();
  }
  if (t == 0) bcast[2] = 0;
  __syncthreads();
  const unsigned long long T = prefix;  // 1024th-largest key
  for (int j = 0; j < 16; ++j) {
    int i = t + 256 * j;
    unsigned long long key = keys[i];
    if (key > T) {
      unsigned pos = atomicAdd(&bcast[2], 1u);
      sel_idx[g * KCAP + pos] = i;
      sel_gate[g * KCAP + pos] = (float)__longlong_as_double(key);
    }
  }
  __syncthreads();
  for (int j = 0; j < 16; ++j) {
    int i = t + 256 * j;
    unsigned long long key = keys[i];
    if (key == T) {
      unsigned pos = atomicAdd(&bcast[2], 1u);
      if (pos < KCAP) {
        sel_idx[g * KCAP + pos] = i;
        sel_gate[g * KCAP + pos] = (float)__longlong_as_double(key);
      }
    }
  }
}

// ---------------- 3. fused gate/up GEMM + SiLU -> h (bf16) ----------------
__global__ __launch_bounds__(256) void moe_gemm1(
    const unsigned short* __restrict__ x, const unsigned short* __restrict__ w_gate,
    const unsigned short* __restrict__ w_up, const int* __restrict__ sel_idx,
    unsigned short* __restrict__ hbuf, int chunk_start) {
  __shared__ __align__(16) unsigned short sA[128 * 32];
  __shared__ __align__(16) unsigned short sG[64 * 32];
  __shared__ __align__(16) unsigned short sU[64 * 32];
  const int gc = blockIdx.z;
  const int g = chunk_start + gc;
  const int e = g >> 2, b = g & 3;
  const int m0 = blockIdx.x * 128, n0 = blockIdx.y * 64;
  const int t = threadIdx.x;
  const int r = t >> 2, c = (t & 3) * 8;

  const int tok0 = sel_idx[g * KCAP + m0 + r] & (S_ - 1);
  const int tok1 = sel_idx[g * KCAP + m0 + 64 + r] & (S_ - 1);
  const unsigned short* gA0 = x + ((size_t)b * S_ + tok0) * D_ + c;
  const unsigned short* gA1 = x + ((size_t)b * S_ + tok1) * D_ + c;
  const unsigned short* gG = w_gate + ((size_t)e * I_ + n0 + r) * D_ + c;
  const unsigned short* gU = w_up + ((size_t)e * I_ + n0 + r) * D_ + c;

  const int wave = t >> 6, lane = t & 63;
  const int wm = wave >> 1, wn = wave & 1;
  const int row16 = lane & 15, quad = lane >> 4;

  floatx4 accg[4][2], accu[4][2];
#pragma unroll
  for (int ms = 0; ms < 4; ++ms)
#pragma unroll
    for (int ns = 0; ns < 2; ++ns) {
      accg[ms][ns] = (floatx4){0.f, 0.f, 0.f, 0.f};
      accu[ms][ns] = (floatx4){0.f, 0.f, 0.f, 0.f};
    }

  for (int k0 = 0; k0 < D_; k0 += 32) {
    uint4 va0 = *(const uint4*)(gA0 + k0);
    uint4 va1 = *(const uint4*)(gA1 + k0);
    uint4 vg = *(const uint4*)(gG + k0);
    uint4 vu = *(const uint4*)(gU + k0);
    __syncthreads();
    *(uint4*)(sA + t * 8) = va0;
    *(uint4*)(sA + 2048 + t * 8) = va1;
    *(uint4*)(sG + t * 8) = vg;
    *(uint4*)(sU + t * 8) = vu;
    __syncthreads();
    bf16x8 a[4], bg[2], bu[2];
#pragma unroll
    for (int ms = 0; ms < 4; ++ms)
      a[ms] = *(const bf16x8*)(sA + (wm * 64 + ms * 16 + row16) * 32 + quad * 8);
#pragma unroll
    for (int ns = 0; ns < 2; ++ns) {
      bg[ns] = *(const bf16x8*)(sG + (wn * 32 + ns * 16 + row16) * 32 + quad * 8);
      bu[ns] = *(const bf16x8*)(sU + (wn * 32 + ns * 16 + row16) * 32 + quad * 8);
    }
#pragma unroll
    for (int ms = 0; ms < 4; ++ms)
#pragma unroll
      for (int ns = 0; ns < 2; ++ns) {
        accg[ms][ns] = __builtin_amdgcn_mfma_f32_16x16x32_bf16(a[ms], bg[ns], accg[ms][ns], 0, 0, 0);
        accu[ms][ns] = __builtin_amdgcn_mfma_f32_16x16x32_bf16(a[ms], bu[ns], accu[ms][ns], 0, 0, 0);
      }
  }
  unsigned short* hb = hbuf + (size_t)gc * ((size_t)KCAP * I_);
#pragma unroll
  for (int ms = 0; ms < 4; ++ms)
#pragma unroll
    for (int ns = 0; ns < 2; ++ns)
#pragma unroll
      for (int r4 = 0; r4 < 4; ++r4) {
        int m = m0 + wm * 64 + ms * 16 + quad * 4 + r4;
        int n = n0 + wn * 32 + ns * 16 + row16;
        float gv = accg[ms][ns][r4], uv = accu[ms][ns][r4];
        float hv = gv / (1.f + __expf(-gv)) * uv;  // silu(g)*u
        hb[(size_t)m * I_ + n] = f2bf(hv);
      }
}

// ---------------- 4. down GEMM + gated fp32 atomic scatter ----------------
__global__ __launch_bounds__(256) void moe_gemm2(
    const unsigned short* __restrict__ hbuf, const unsigned short* __restrict__ w_down,
    const int* __restrict__ sel_idx, const float* __restrict__ sel_gate,
    float* __restrict__ acc_out, int chunk_start) {
  __shared__ __align__(16) unsigned short sA[128 * 32];
  __shared__ __align__(16) unsigned short sB[128 * 32];
  __shared__ int stok[128];
  __shared__ float sgt[128];
  const int gc = blockIdx.z;
  const int g = chunk_start + gc;
  const int e = g >> 2, b = g & 3;
  const int m0 = blockIdx.x * 128, n0 = blockIdx.y * 128;
  const int t = threadIdx.x;
  const int r = t >> 2, c = (t & 3) * 8;
  if (t < 128) {
    stok[t] = sel_idx[g * KCAP + m0 + t] & (S_ - 1);
    sgt[t] = sel_gate[g * KCAP + m0 + t];
  }
  const unsigned short* gA0 = hbuf + (size_t)gc * ((size_t)KCAP * I_) + (size_t)(m0 + r) * I_ + c;
  const unsigned short* gA1 = gA0 + (size_t)64 * I_;
  const unsigned short* gB0 = w_down + ((size_t)e * D_ + n0 + r) * I_ + c;
  const unsigned short* gB1 = gB0 + (size_t)64 * I_;
  const int wave = t >> 6, lane = t & 63;
  const int wm = wave >> 1, wn = wave & 1;
  const int row16 = lane & 15, quad = lane >> 4;
  floatx4 accf[4][4];
#pragma unroll
  for (int ms = 0; ms < 4; ++ms)
#pragma unroll
    for (int ns = 0; ns < 4; ++ns) accf[ms][ns] = (floatx4){0.f, 0.f, 0.f, 0.f};

  for (int k0 = 0; k0 < I_; k0 += 32) {
    uint4 va0 = *(const uint4*)(gA0 + k0);
    uint4 va1 = *(const uint4*)(gA1 + k0);
    uint4 vb0 = *(const uint4*)(gB0 + k0);
    uint4 vb1 = *(const uint4*)(gB1 + k0);
    __syncthreads();
    *(uint4*)(sA + t * 8) = va0;
    *(uint4*)(sA + 2048 + t * 8) = va1;
    *(uint4*)(sB + t * 8) = vb0;
    *(uint4*)(sB + 2048 + t * 8) = vb1;
    __syncthreads();
    bf16x8 a[4], bb[4];
#pragma unroll
    for (int i = 0; i < 4; ++i) {
      a[i] = *(const bf16x8*)(sA + (wm * 64 + i * 16 + row16) * 32 + quad * 8);
      bb[i] = *(const bf16x8*)(sB + (wn * 64 + i * 16 + row16) * 32 + quad * 8);
    }
#pragma unroll
    for (int ms = 0; ms < 4; ++ms)
#pragma unroll
      for (int ns = 0; ns < 4; ++ns)
        accf[ms][ns] = __builtin_amdgcn_mfma_f32_16x16x32_bf16(a[ms], bb[ns], accf[ms][ns], 0, 0, 0);
  }
#pragma unroll
  for (int ms = 0; ms < 4; ++ms)
#pragma unroll
    for (int r4 = 0; r4 < 4; ++r4) {
      int mloc = wm * 64 + ms * 16 + quad * 4 + r4;
      int tok = stok[mloc];
      float gt = sgt[mloc];
      float* basep = acc_out + ((size_t)b * S_ + tok) * D_ + n0 + wn * 64 + row16;
#pragma unroll
      for (int ns = 0; ns < 4; ++ns) unsafeAtomicAdd(basep + ns * 16, accf[ms][ns][r4] * gt);
    }
}

// ---------------- 5. fp32 accumulator -> output (dtype per flag) ----------------
__global__ __launch_bounds__(256) void conv_out_k(const float* __restrict__ acc,
                                                  void* __restrict__ out,
                                                  const int* __restrict__ flag) {
  const int isf32 = *flag;
  size_t i = ((size_t)blockIdx.x * 256 + threadIdx.x) * 4;
  float4 v = *(const float4*)(acc + i);
  if (isf32) {
    *(float4*)((float*)out + i) = v;
  } else {
    ushort4 o;
    o.x = f2bf(v.x); o.y = f2bf(v.y); o.z = f2bf(v.z); o.w = f2bf(v.w);
    *(ushort4*)((unsigned short*)out + i) = o;
  }
}

extern "C" void kernel_launch(void* const* d_in, const int* in_sizes, int n_in,
                              void* d_out, int out_size, void* d_ws, size_t ws_size,
                              hipStream_t stream) {
  const void* x_raw = d_in[0];
  const void* gate_w_raw = d_in[1];
  const void* w_gate_raw = d_in[2];
  const void* w_up_raw = d_in[3];
  const void* w_down_raw = d_in[4];

  char* ws = (char*)d_ws;
  size_t off = 0;
  auto alloc = [&](size_t bytes) { char* p = ws + off; off += (bytes + 255) & ~(size_t)255; return p; };
  float* acc = (float*)alloc((size_t)B_ * S_ * D_ * 4);          // 64 MB
  double* aff = (double*)alloc((size_t)B_ * E_ * S_ * 8);        // 1 MB
  int* sel_idx = (int*)alloc((size_t)NGROUPS * KCAP * 4);        // 128 KB
  float* sel_gate = (float*)alloc((size_t)NGROUPS * KCAP * 4);   // 128 KB
  int* flag = (int*)alloc(256);
  unsigned short* xb = (unsigned short*)alloc((size_t)B_ * S_ * D_ * 2);    // 33.5 MB
  unsigned short* wgb = (unsigned short*)alloc((size_t)E_ * I_ * D_ * 2);   // 67 MB
  unsigned short* wub = (unsigned short*)alloc((size_t)E_ * I_ * D_ * 2);   // 67 MB
  unsigned short* wdb = (unsigned short*)alloc((size_t)E_ * D_ * I_ * 2);   // 67 MB
  const size_t fixedBytes = off;
  const size_t hPerGroup = (size_t)KCAP * I_ * 2;  // 8 MB bf16
  int gch = 32;
  while (gch > 1 && fixedBytes + (size_t)gch * hPerGroup > ws_size) gch >>= 1;
  unsigned short* hbuf = (unsigned short*)(ws + fixedBytes);

  hipMemsetAsync(acc, 0, (size_t)B_ * S_ * D_ * 4, stream);
  hipMemsetAsync(sel_idx, 0, (size_t)NGROUPS * KCAP * 8, stream);

  probe_dtype_k<<<dim3(1), dim3(256), 0, stream>>>((const unsigned short*)x_raw, flag);
  conv_in_k<<<dim3((int)((size_t)B_ * S_ * D_ / 2048)), dim3(256), 0, stream>>>(x_raw, xb, flag);
  conv_in_k<<<dim3((int)((size_t)E_ * I_ * D_ / 2048)), dim3(256), 0, stream>>>(w_gate_raw, wgb, flag);
  conv_in_k<<<dim3((int)((size_t)E_ * I_ * D_ / 2048)), dim3(256), 0, stream>>>(w_up_raw, wub, flag);
  conv_in_k<<<dim3((int)((size_t)E_ * D_ * I_ / 2048)), dim3(256), 0, stream>>>(w_down_raw, wdb, flag);

  gate_softmax_k<<<dim3(B_ * S_ / 4), dim3(256), 0, stream>>>(x_raw, gate_w_raw, flag, aff);
  topk_sel_k<<<dim3(NGROUPS), dim3(256), 0, stream>>>(aff, sel_idx, sel_gate);
  for (int c0 = 0; c0 < NGROUPS; c0 += gch) {
    int gcur = (NGROUPS - c0) < gch ? (NGROUPS - c0) : gch;
    moe_gemm1<<<dim3(KCAP / 128, I_ / 64, gcur), dim3(256), 0, stream>>>(
        xb, wgb, wub, sel_idx, hbuf, c0);
    moe_gemm2<<<dim3(KCAP / 128, D_ / 128, gcur), dim3(256), 0, stream>>>(
        hbuf, wdb, sel_idx, sel_gate, acc, c0);
  }
  conv_out_k<<<dim3((int)((size_t)B_ * S_ * D_ / 4 / 256)), dim3(256), 0, stream>>>(acc, d_out, flag);
}